// Round 7
// baseline (1346.272 us; speedup 1.0000x reference)
//
#include <hip/hip_runtime.h>
#include <math.h>

#define N_NODES 12288
#define F_IN    256
#define H_DIM   64
#define C_OUT   16
#define MAXD    192
#define NC      (N_NODES * C_OUT)
#define GRPB    32   // rows per gemm block (merged kernel)
#define LW      4    // rows (waves) per gcn_layer block

typedef unsigned short ushort_t;
typedef unsigned int uv4 __attribute__((ext_vector_type(4)));

__device__ __forceinline__ float bf2f(unsigned int u) {
    union { unsigned int i; float f; } p;
    p.i = (u & 0xFFFFu) << 16;
    return p.f;
}
__device__ __forceinline__ ushort_t f2bf(float f) {
    union { float f; unsigned int i; } p;
    p.f = f;
    unsigned int u = p.i;
    u += 0x7FFFu + ((u >> 16) & 1u);   // round-to-nearest-even
    return (ushort_t)(u >> 16);
}

// ---------------------------------------------------------------------------
// Kernel A: merged adjacency scan + input GEMM (independent work, one dispatch).
// Blocks [0, N_NODES): scan one adj row -> ELL + deg + dinv. All 12 uv4 loads
//   hoisted upfront per thread (12 outstanding -> hides HBM latency).
// Blocks [N_NODES, N_NODES+384): h0 = x @ W_in + b_in for 32 rows (fp32+bf16).
// ---------------------------------------------------------------------------
__global__ __launch_bounds__(256) void scan_and_gemm(
    const float* __restrict__ adj, int* __restrict__ ell,
    int* __restrict__ cnt, float* __restrict__ dinv,
    const float* __restrict__ x, const float* __restrict__ Win,
    const float* __restrict__ bin, float* __restrict__ h0,
    ushort_t* __restrict__ h0b, unsigned int* __restrict__ counter) {
    __shared__ float xs[GRPB][F_IN];   // 32 KB (gemm branch)
    __shared__ int scnt;               // (scan branch)
    int t = threadIdx.x;
    if (blockIdx.x < N_NODES) {
        int u = blockIdx.x;
        if (t == 0) scnt = 0;
        if (u == 0 && t == 0) *counter = 0u;   // for energy's last-block pattern
        __syncthreads();
        const uv4* rp = (const uv4*)(adj + (size_t)u * N_NODES);
        uv4 v[12];
#pragma unroll
        for (int q = 0; q < 12; q++)
            v[q] = __builtin_nontemporal_load(&rp[t + q * 256]);
#pragma unroll
        for (int q = 0; q < 12; q++) {
            uv4 w = v[q];
            if ((w.x | w.y | w.z | w.w) == 0u) continue;
            int col = (t + q * 256) * 4;
            if (w.x) { int s = atomicAdd(&scnt, 1); if (s < MAXD) ell[(size_t)u * MAXD + s] = col + 0; }
            if (w.y) { int s = atomicAdd(&scnt, 1); if (s < MAXD) ell[(size_t)u * MAXD + s] = col + 1; }
            if (w.z) { int s = atomicAdd(&scnt, 1); if (s < MAXD) ell[(size_t)u * MAXD + s] = col + 2; }
            if (w.w) { int s = atomicAdd(&scnt, 1); if (s < MAXD) ell[(size_t)u * MAXD + s] = col + 3; }
        }
        __syncthreads();
        if (t == 0) {
            cnt[u] = scnt;                       // diag excluded by ref's adj
            dinv[u] = rsqrtf((float)(scnt + 1)); // A = adj + I -> deg = cnt + 1
        }
    } else {
        int row0 = (blockIdx.x - N_NODES) * GRPB;
        const float4* xp = (const float4*)(x + (size_t)row0 * F_IN);
        for (int i = t; i < GRPB * F_IN / 4; i += 256) ((float4*)xs)[i] = xp[i];
        __syncthreads();
        int c4 = (t & 15) * 4;   // 4 output columns
        int rs = t >> 4;         // rows rs and rs+16 of the tile
        float4 acc0 = make_float4(0.f, 0.f, 0.f, 0.f);
        float4 acc1 = make_float4(0.f, 0.f, 0.f, 0.f);
        for (int k = 0; k < F_IN; k += 4) {
            float4 w0 = *(const float4*)&Win[(k + 0) * H_DIM + c4];
            float4 w1 = *(const float4*)&Win[(k + 1) * H_DIM + c4];
            float4 w2 = *(const float4*)&Win[(k + 2) * H_DIM + c4];
            float4 w3 = *(const float4*)&Win[(k + 3) * H_DIM + c4];
            float4 xa = *(const float4*)&xs[rs][k];
            float4 xb = *(const float4*)&xs[rs + 16][k];
            acc0.x += xa.x * w0.x + xa.y * w1.x + xa.z * w2.x + xa.w * w3.x;
            acc0.y += xa.x * w0.y + xa.y * w1.y + xa.z * w2.y + xa.w * w3.y;
            acc0.z += xa.x * w0.z + xa.y * w1.z + xa.z * w2.z + xa.w * w3.z;
            acc0.w += xa.x * w0.w + xa.y * w1.w + xa.z * w2.w + xa.w * w3.w;
            acc1.x += xb.x * w0.x + xb.y * w1.x + xb.z * w2.x + xb.w * w3.x;
            acc1.y += xb.x * w0.y + xb.y * w1.y + xb.z * w2.y + xb.w * w3.y;
            acc1.z += xb.x * w0.z + xb.y * w1.z + xb.z * w2.z + xb.w * w3.z;
            acc1.w += xb.x * w0.w + xb.y * w1.w + xb.z * w2.w + xb.w * w3.w;
        }
        float4 bb = *(const float4*)&bin[c4];
        acc0.x += bb.x; acc0.y += bb.y; acc0.z += bb.z; acc0.w += bb.w;
        acc1.x += bb.x; acc1.y += bb.y; acc1.z += bb.z; acc1.w += bb.w;
        *(float4*)&h0[(size_t)(row0 + rs) * H_DIM + c4] = acc0;
        *(float4*)&h0[(size_t)(row0 + rs + 16) * H_DIM + c4] = acc1;
        ushort_t* pb0 = &h0b[(size_t)(row0 + rs) * H_DIM + c4];
        pb0[0] = f2bf(acc0.x); pb0[1] = f2bf(acc0.y); pb0[2] = f2bf(acc0.z); pb0[3] = f2bf(acc0.w);
        ushort_t* pb1 = &h0b[(size_t)(row0 + rs + 16) * H_DIM + c4];
        pb1[0] = f2bf(acc1.x); pb1[1] = f2bf(acc1.y); pb1[2] = f2bf(acc1.z); pb1[3] = f2bf(acc1.w);
    }
}

// ---------------------------------------------------------------------------
// Kernel B (x4): fused GCNII layer. 256 thr = 4 waves, wave = one row u,
// lane = channel j. bf16 gathers; fp32 residual; Wc staged in LDS.
// ---------------------------------------------------------------------------
__global__ __launch_bounds__(256) void gcn_layer(
    const ushort_t* __restrict__ h_in, const float* __restrict__ h0,
    const int* __restrict__ ell, const int* __restrict__ cnt,
    const float* __restrict__ dinv, const float* __restrict__ Wc,
    const float* __restrict__ lng, const float* __restrict__ lnb,
    float beta, int do_ln, ushort_t* __restrict__ hb_out,
    float* __restrict__ hf_out) {
    __shared__ float wcs[H_DIM * H_DIM];      // 16 KB
    __shared__ int   nvs[LW][MAXD];
    __shared__ float ndvs[LW][MAXD];
    int t = threadIdx.x;
    int w = t >> 6, j = t & 63;
    const float4* wp = (const float4*)Wc;
    for (int i = t; i < H_DIM * H_DIM / 4; i += 256) ((float4*)wcs)[i] = wp[i];
    int u = blockIdx.x * LW + w;
    int c = cnt[u]; if (c > MAXD) c = MAXD;
    for (int e = j; e < c; e += 64) {
        int v = ell[(size_t)u * MAXD + e];
        nvs[w][e] = v;
        ndvs[w][e] = dinv[v];
    }
    __syncthreads();
    float du = dinv[u];
    float hself = bf2f(h_in[(size_t)u * H_DIM + j]);
    float h0v = h0[(size_t)u * H_DIM + j];
    float a[8];
#pragma unroll
    for (int q = 0; q < 8; q++) a[q] = 0.f;
    int e = 0;
    for (; e + 8 <= c; e += 8) {
#pragma unroll
        for (int q = 0; q < 8; q++)
            a[q] += ndvs[w][e + q] * bf2f(h_in[(size_t)nvs[w][e + q] * H_DIM + j]);
    }
    for (; e < c; e++)
        a[0] += ndvs[w][e] * bf2f(h_in[(size_t)nvs[w][e] * H_DIM + j]);
    float acc = du * hself + (((a[0] + a[1]) + (a[2] + a[3])) + ((a[4] + a[5]) + (a[6] + a[7])));
    float hm = 0.7f * (du * acc) + 0.3f * h0v;
    float mv = 0.f;
#pragma unroll 8
    for (int k = 0; k < H_DIM; k++)
        mv += __shfl(hm, k) * wcs[k * H_DIM + j];
    float hn = (1.f - beta) * hm + beta * mv;
    if (do_ln) {
        hn = fmaxf(hn, 0.f);                      // relu
        float ssum = hn;
#pragma unroll
        for (int off = 32; off; off >>= 1) ssum += __shfl_xor(ssum, off);
        float mu = ssum * (1.f / 64.f);
        float d = hn - mu;
        float vsum = d * d;
#pragma unroll
        for (int off = 32; off; off >>= 1) vsum += __shfl_xor(vsum, off);
        float var = vsum * (1.f / 64.f);
        hn = d * rsqrtf(var + 1e-5f) * lng[j] + lnb[j];
        hb_out[(size_t)u * H_DIM + j] = f2bf(hn);
    } else {
        hf_out[(size_t)u * H_DIM + j] = hn;
    }
}

// ---------------------------------------------------------------------------
// Kernel C: out = h @ W_out + b_out; out + log_softmax; g = relu/sqrt(deg+2).
// ---------------------------------------------------------------------------
__global__ __launch_bounds__(256) void out_head(
    const float* __restrict__ h, const float* __restrict__ Wout,
    const float* __restrict__ bout, const int* __restrict__ cnt,
    float* __restrict__ dout, float* __restrict__ g) {
    __shared__ float hs[16 * H_DIM];
    int t = threadIdx.x;
    int rb = blockIdx.x * 16;
    const float4* hp = (const float4*)(h + (size_t)rb * H_DIM);
    for (int i = t; i < 16 * H_DIM / 4; i += 256) ((float4*)hs)[i] = hp[i];
    __syncthreads();
    int r = t >> 4, ci = t & 15;
    int row = rb + r;
    float acc = bout[ci];
#pragma unroll 8
    for (int k = 0; k < H_DIM; k++)
        acc += hs[r * H_DIM + k] * Wout[k * C_OUT + ci];
    dout[(size_t)row * C_OUT + ci] = acc;
    float m = acc;
#pragma unroll
    for (int off = 8; off; off >>= 1) m = fmaxf(m, __shfl_xor(m, off, 16));
    float e = expf(acc - m);
    float se = e;
#pragma unroll
    for (int off = 8; off; off >>= 1) se += __shfl_xor(se, off, 16);
    dout[(size_t)NC + (size_t)row * C_OUT + ci] = acc - m - logf(se);
    g[(size_t)row * C_OUT + ci] = fmaxf(acc, 0.f) * rsqrtf((float)(cnt[row] + 2));
}

// ---------------------------------------------------------------------------
// Kernel D: Dirichlet energy partials + last-block final reduction (one dispatch).
// de_u = rowsumW_u*|g_u|^2 - (Wc g)_u . g_u ;  pe[u] = {de_u, rowsumW_u}
// Last finishing block reduces pe and writes the scalar (threadfence pattern).
// ---------------------------------------------------------------------------
__global__ __launch_bounds__(64) void energy(
    const float* __restrict__ g, const int* __restrict__ ell,
    const int* __restrict__ cnt, const float* __restrict__ dinv,
    float2* __restrict__ pe, unsigned int* __restrict__ counter,
    float* __restrict__ dout) {
    int u = blockIdx.x;
    int j = threadIdx.x;
    int ci = j & 15, sub = j >> 4;
    __shared__ int nv[MAXD];
    __shared__ float ndv[MAXD];
    __shared__ bool isLast;
    int c = cnt[u]; if (c > MAXD) c = MAXD;
    for (int e = j; e < c; e += 64) {
        int v = ell[(size_t)u * MAXD + e];
        nv[e] = v;
        ndv[e] = dinv[v];
    }
    __syncthreads();
    float du = dinv[u];
    float ag0 = 0.f, ag1 = 0.f, accd = 0.f;
    int e = sub;
    for (; e + 8 <= c; e += 8) {
        float d0 = ndv[e], d1 = ndv[e + 4];
        ag0 += d0 * g[(size_t)nv[e] * C_OUT + ci];
        ag1 += d1 * g[(size_t)nv[e + 4] * C_OUT + ci];
        if (ci == 0) accd += d0 + d1;
    }
    for (; e < c; e += 4) {
        float dv = ndv[e];
        ag0 += dv * g[(size_t)nv[e] * C_OUT + ci];
        if (ci == 0) accd += dv;
    }
    float accg = ag0 + ag1;
    accg += __shfl_xor(accg, 16);
    accg += __shfl_xor(accg, 32);
    accd += __shfl_xor(accd, 16);
    accd += __shfl_xor(accd, 32);
    float gu = g[(size_t)u * C_OUT + ci];
    float wg = du * (du * gu + accg);   // (Wc g)_u[ci]
    float part = wg * gu;
    float sc = gu * gu;
#pragma unroll
    for (int off = 8; off; off >>= 1) {
        part += __shfl_xor(part, off, 16);
        sc += __shfl_xor(sc, off, 16);
    }
    if (j == 0) {
        float rowsum = du * (du + accd);
        pe[u] = make_float2(rowsum * sc - part, rowsum);
    }
    // last-block-done final reduction
    __threadfence();
    if (j == 0) {
        unsigned int old = atomicAdd(counter, 1u);
        isLast = (old == (unsigned int)(gridDim.x - 1));
    }
    __syncthreads();
    if (isLast) {
        __threadfence();
        volatile float2* vp = (volatile float2*)pe;
        float s0 = 0.f, s1 = 0.f;
        for (int i = j; i < N_NODES; i += 64) {
            float2 p; p.x = vp[i].x; p.y = vp[i].y;
            s0 += p.x; s1 += p.y;
        }
#pragma unroll
        for (int off = 32; off; off >>= 1) {
            s0 += __shfl_xor(s0, off);
            s1 += __shfl_xor(s1, off);
        }
        if (j == 0) dout[(size_t)2 * NC] = s0 / s1;
    }
}

extern "C" void kernel_launch(void* const* d_in, const int* in_sizes, int n_in,
                              void* d_out, int out_size, void* d_ws, size_t ws_size,
                              hipStream_t stream) {
    const float* x    = (const float*)d_in[0];
    const float* adj  = (const float*)d_in[1];
    const float* Win  = (const float*)d_in[2];
    const float* bin  = (const float*)d_in[3];
    const float* Wcv  = (const float*)d_in[4];
    const float* lng  = (const float*)d_in[5];
    const float* lnb  = (const float*)d_in[6];
    const float* Wout = (const float*)d_in[7];
    const float* bout = (const float*)d_in[8];

    char* ws = (char*)d_ws;
    size_t off = 0;
    auto alloc = [&](size_t bytes) -> void* {
        void* p = ws + off;
        off = (off + bytes + 255) & ~(size_t)255;
        return p;
    };
    int*          ell  = (int*)         alloc((size_t)N_NODES * MAXD * sizeof(int));
    int*          cnt  = (int*)         alloc((size_t)N_NODES * sizeof(int));
    float*        dinv = (float*)       alloc((size_t)N_NODES * sizeof(float));
    float*        h0   = (float*)       alloc((size_t)N_NODES * H_DIM * sizeof(float));
    ushort_t*     h0b  = (ushort_t*)    alloc((size_t)N_NODES * H_DIM * sizeof(ushort_t));
    ushort_t*     ha   = (ushort_t*)    alloc((size_t)N_NODES * H_DIM * sizeof(ushort_t));
    ushort_t*     hb   = (ushort_t*)    alloc((size_t)N_NODES * H_DIM * sizeof(ushort_t));
    float*        hf   = (float*)       alloc((size_t)N_NODES * H_DIM * sizeof(float));
    float*        g    = (float*)       alloc((size_t)N_NODES * C_OUT * sizeof(float));
    float2*       pe   = (float2*)      alloc((size_t)N_NODES * sizeof(float2));
    unsigned int* ctr  = (unsigned int*)alloc(256);

    scan_and_gemm<<<N_NODES + N_NODES / GRPB, 256, 0, stream>>>(
        adj, ell, cnt, dinv, x, Win, bin, h0, h0b, ctr);

    const ushort_t* hin = h0b;
    ushort_t* bbufs[2] = { ha, hb };
    for (int i = 0; i < 4; i++) {
        float beta = logf(0.3f / (float)(i + 1) + 1.f);
        ushort_t* hbo = bbufs[i & 1];
        gcn_layer<<<N_NODES / LW, 256, 0, stream>>>(
            hin, h0, ell, cnt, dinv,
            Wcv + (size_t)i * H_DIM * H_DIM, lng + i * H_DIM, lnb + i * H_DIM,
            beta, (i != 3) ? 1 : 0, hbo, hf);
        hin = hbo;
    }

    out_head<<<N_NODES / 16, 256, 0, stream>>>(hf, Wout, bout, cnt,
                                               (float*)d_out, g);
    energy<<<N_NODES, 64, 0, stream>>>(g, ell, cnt, dinv, pe, ctr, (float*)d_out);
}

// Round 8
// 890.719 us; speedup vs baseline: 1.5114x; 1.5114x over previous
//
#include <hip/hip_runtime.h>
#include <math.h>

#define N_NODES 12288
#define F_IN    256
#define H_DIM   64
#define C_OUT   16
#define MAXD    192
#define NC      (N_NODES * C_OUT)
#define GRPB    32   // rows per gemm block (merged kernel)
#define LW      4    // rows (waves) per gcn_layer block

typedef unsigned short ushort_t;
typedef unsigned int uv4 __attribute__((ext_vector_type(4)));

__device__ __forceinline__ float bf2f(unsigned int u) {
    union { unsigned int i; float f; } p;
    p.i = (u & 0xFFFFu) << 16;
    return p.f;
}
__device__ __forceinline__ ushort_t f2bf(float f) {
    union { float f; unsigned int i; } p;
    p.f = f;
    unsigned int u = p.i;
    u += 0x7FFFu + ((u >> 16) & 1u);   // round-to-nearest-even
    return (ushort_t)(u >> 16);
}

// ---------------------------------------------------------------------------
// Kernel A: merged adjacency scan + input GEMM (independent work, one dispatch).
// Blocks [0, N_NODES): scan one adj row -> ELL + deg + dinv; 12 nontemporal
//   uv4 loads hoisted upfront (12 outstanding -> hides HBM latency).
// Blocks [N_NODES, N_NODES+384): h0 = x @ W_in + b_in for 32 rows (fp32+bf16).
// ---------------------------------------------------------------------------
__global__ __launch_bounds__(256) void scan_and_gemm(
    const float* __restrict__ adj, int* __restrict__ ell,
    int* __restrict__ cnt, float* __restrict__ dinv,
    const float* __restrict__ x, const float* __restrict__ Win,
    const float* __restrict__ bin, float* __restrict__ h0,
    ushort_t* __restrict__ h0b) {
    __shared__ float xs[GRPB][F_IN];   // 32 KB (gemm branch)
    __shared__ int scnt;               // (scan branch)
    int t = threadIdx.x;
    if (blockIdx.x < N_NODES) {
        int u = blockIdx.x;
        if (t == 0) scnt = 0;
        __syncthreads();
        const uv4* rp = (const uv4*)(adj + (size_t)u * N_NODES);
        uv4 v[12];
#pragma unroll
        for (int q = 0; q < 12; q++)
            v[q] = __builtin_nontemporal_load(&rp[t + q * 256]);
#pragma unroll
        for (int q = 0; q < 12; q++) {
            uv4 w = v[q];
            if ((w.x | w.y | w.z | w.w) == 0u) continue;
            int col = (t + q * 256) * 4;
            if (w.x) { int s = atomicAdd(&scnt, 1); if (s < MAXD) ell[(size_t)u * MAXD + s] = col + 0; }
            if (w.y) { int s = atomicAdd(&scnt, 1); if (s < MAXD) ell[(size_t)u * MAXD + s] = col + 1; }
            if (w.z) { int s = atomicAdd(&scnt, 1); if (s < MAXD) ell[(size_t)u * MAXD + s] = col + 2; }
            if (w.w) { int s = atomicAdd(&scnt, 1); if (s < MAXD) ell[(size_t)u * MAXD + s] = col + 3; }
        }
        __syncthreads();
        if (t == 0) {
            cnt[u] = scnt;                       // diag excluded by ref's adj
            dinv[u] = rsqrtf((float)(scnt + 1)); // A = adj + I -> deg = cnt + 1
        }
    } else {
        int row0 = (blockIdx.x - N_NODES) * GRPB;
        const float4* xp = (const float4*)(x + (size_t)row0 * F_IN);
        for (int i = t; i < GRPB * F_IN / 4; i += 256) ((float4*)xs)[i] = xp[i];
        __syncthreads();
        int c4 = (t & 15) * 4;   // 4 output columns
        int rs = t >> 4;         // rows rs and rs+16 of the tile
        float4 acc0 = make_float4(0.f, 0.f, 0.f, 0.f);
        float4 acc1 = make_float4(0.f, 0.f, 0.f, 0.f);
        for (int k = 0; k < F_IN; k += 4) {
            float4 w0 = *(const float4*)&Win[(k + 0) * H_DIM + c4];
            float4 w1 = *(const float4*)&Win[(k + 1) * H_DIM + c4];
            float4 w2 = *(const float4*)&Win[(k + 2) * H_DIM + c4];
            float4 w3 = *(const float4*)&Win[(k + 3) * H_DIM + c4];
            float4 xa = *(const float4*)&xs[rs][k];
            float4 xb = *(const float4*)&xs[rs + 16][k];
            acc0.x += xa.x * w0.x + xa.y * w1.x + xa.z * w2.x + xa.w * w3.x;
            acc0.y += xa.x * w0.y + xa.y * w1.y + xa.z * w2.y + xa.w * w3.y;
            acc0.z += xa.x * w0.z + xa.y * w1.z + xa.z * w2.z + xa.w * w3.z;
            acc0.w += xa.x * w0.w + xa.y * w1.w + xa.z * w2.w + xa.w * w3.w;
            acc1.x += xb.x * w0.x + xb.y * w1.x + xb.z * w2.x + xb.w * w3.x;
            acc1.y += xb.x * w0.y + xb.y * w1.y + xb.z * w2.y + xb.w * w3.y;
            acc1.z += xb.x * w0.z + xb.y * w1.z + xb.z * w2.z + xb.w * w3.z;
            acc1.w += xb.x * w0.w + xb.y * w1.w + xb.z * w2.w + xb.w * w3.w;
        }
        float4 bb = *(const float4*)&bin[c4];
        acc0.x += bb.x; acc0.y += bb.y; acc0.z += bb.z; acc0.w += bb.w;
        acc1.x += bb.x; acc1.y += bb.y; acc1.z += bb.z; acc1.w += bb.w;
        *(float4*)&h0[(size_t)(row0 + rs) * H_DIM + c4] = acc0;
        *(float4*)&h0[(size_t)(row0 + rs + 16) * H_DIM + c4] = acc1;
        ushort_t* pb0 = &h0b[(size_t)(row0 + rs) * H_DIM + c4];
        pb0[0] = f2bf(acc0.x); pb0[1] = f2bf(acc0.y); pb0[2] = f2bf(acc0.z); pb0[3] = f2bf(acc0.w);
        ushort_t* pb1 = &h0b[(size_t)(row0 + rs + 16) * H_DIM + c4];
        pb1[0] = f2bf(acc1.x); pb1[1] = f2bf(acc1.y); pb1[2] = f2bf(acc1.z); pb1[3] = f2bf(acc1.w);
    }
}

// ---------------------------------------------------------------------------
// Kernel B (x4): fused GCNII layer. 256 thr = 4 waves, wave = one row u,
// lane = channel j. bf16 gathers; fp32 residual; Wc staged in LDS.
// ---------------------------------------------------------------------------
__global__ __launch_bounds__(256) void gcn_layer(
    const ushort_t* __restrict__ h_in, const float* __restrict__ h0,
    const int* __restrict__ ell, const int* __restrict__ cnt,
    const float* __restrict__ dinv, const float* __restrict__ Wc,
    const float* __restrict__ lng, const float* __restrict__ lnb,
    float beta, int do_ln, ushort_t* __restrict__ hb_out,
    float* __restrict__ hf_out) {
    __shared__ float wcs[H_DIM * H_DIM];      // 16 KB
    __shared__ int   nvs[LW][MAXD];
    __shared__ float ndvs[LW][MAXD];
    int t = threadIdx.x;
    int w = t >> 6, j = t & 63;
    const float4* wp = (const float4*)Wc;
    for (int i = t; i < H_DIM * H_DIM / 4; i += 256) ((float4*)wcs)[i] = wp[i];
    int u = blockIdx.x * LW + w;
    int c = cnt[u]; if (c > MAXD) c = MAXD;
    for (int e = j; e < c; e += 64) {
        int v = ell[(size_t)u * MAXD + e];
        nvs[w][e] = v;
        ndvs[w][e] = dinv[v];
    }
    __syncthreads();
    float du = dinv[u];
    float hself = bf2f(h_in[(size_t)u * H_DIM + j]);
    float h0v = h0[(size_t)u * H_DIM + j];
    float a[8];
#pragma unroll
    for (int q = 0; q < 8; q++) a[q] = 0.f;
    int e = 0;
    for (; e + 8 <= c; e += 8) {
#pragma unroll
        for (int q = 0; q < 8; q++)
            a[q] += ndvs[w][e + q] * bf2f(h_in[(size_t)nvs[w][e + q] * H_DIM + j]);
    }
    for (; e < c; e++)
        a[0] += ndvs[w][e] * bf2f(h_in[(size_t)nvs[w][e] * H_DIM + j]);
    float acc = du * hself + (((a[0] + a[1]) + (a[2] + a[3])) + ((a[4] + a[5]) + (a[6] + a[7])));
    float hm = 0.7f * (du * acc) + 0.3f * h0v;
    float mv = 0.f;
#pragma unroll 8
    for (int k = 0; k < H_DIM; k++)
        mv += __shfl(hm, k) * wcs[k * H_DIM + j];
    float hn = (1.f - beta) * hm + beta * mv;
    if (do_ln) {
        hn = fmaxf(hn, 0.f);                      // relu
        float ssum = hn;
#pragma unroll
        for (int off = 32; off; off >>= 1) ssum += __shfl_xor(ssum, off);
        float mu = ssum * (1.f / 64.f);
        float d = hn - mu;
        float vsum = d * d;
#pragma unroll
        for (int off = 32; off; off >>= 1) vsum += __shfl_xor(vsum, off);
        float var = vsum * (1.f / 64.f);
        hn = d * rsqrtf(var + 1e-5f) * lng[j] + lnb[j];
        hb_out[(size_t)u * H_DIM + j] = f2bf(hn);
    } else {
        hf_out[(size_t)u * H_DIM + j] = hn;
    }
}

// ---------------------------------------------------------------------------
// Kernel C: out = h @ W_out + b_out; out + log_softmax; g = relu/sqrt(deg+2).
// ---------------------------------------------------------------------------
__global__ __launch_bounds__(256) void out_head(
    const float* __restrict__ h, const float* __restrict__ Wout,
    const float* __restrict__ bout, const int* __restrict__ cnt,
    float* __restrict__ dout, float* __restrict__ g) {
    __shared__ float hs[16 * H_DIM];
    int t = threadIdx.x;
    int rb = blockIdx.x * 16;
    const float4* hp = (const float4*)(h + (size_t)rb * H_DIM);
    for (int i = t; i < 16 * H_DIM / 4; i += 256) ((float4*)hs)[i] = hp[i];
    __syncthreads();
    int r = t >> 4, ci = t & 15;
    int row = rb + r;
    float acc = bout[ci];
#pragma unroll 8
    for (int k = 0; k < H_DIM; k++)
        acc += hs[r * H_DIM + k] * Wout[k * C_OUT + ci];
    dout[(size_t)row * C_OUT + ci] = acc;
    float m = acc;
#pragma unroll
    for (int off = 8; off; off >>= 1) m = fmaxf(m, __shfl_xor(m, off, 16));
    float e = expf(acc - m);
    float se = e;
#pragma unroll
    for (int off = 8; off; off >>= 1) se += __shfl_xor(se, off, 16);
    dout[(size_t)NC + (size_t)row * C_OUT + ci] = acc - m - logf(se);
    g[(size_t)row * C_OUT + ci] = fmaxf(acc, 0.f) * rsqrtf((float)(cnt[row] + 2));
}

// ---------------------------------------------------------------------------
// Kernel D: Dirichlet energy partials (NO global atomics — per-row float2).
// de_u = rowsumW_u*|g_u|^2 - (Wc g)_u . g_u ;  pe[u] = {de_u, rowsumW_u}
// ---------------------------------------------------------------------------
__global__ __launch_bounds__(64) void energy(
    const float* __restrict__ g, const int* __restrict__ ell,
    const int* __restrict__ cnt, const float* __restrict__ dinv,
    float2* __restrict__ pe) {
    int u = blockIdx.x;
    int j = threadIdx.x;
    int ci = j & 15, sub = j >> 4;
    __shared__ int nv[MAXD];
    __shared__ float ndv[MAXD];
    int c = cnt[u]; if (c > MAXD) c = MAXD;
    for (int e = j; e < c; e += 64) {
        int v = ell[(size_t)u * MAXD + e];
        nv[e] = v;
        ndv[e] = dinv[v];
    }
    __syncthreads();
    float du = dinv[u];
    float ag0 = 0.f, ag1 = 0.f, accd = 0.f;
    int e = sub;
    for (; e + 8 <= c; e += 8) {
        float d0 = ndv[e], d1 = ndv[e + 4];
        ag0 += d0 * g[(size_t)nv[e] * C_OUT + ci];
        ag1 += d1 * g[(size_t)nv[e + 4] * C_OUT + ci];
        if (ci == 0) accd += d0 + d1;
    }
    for (; e < c; e += 4) {
        float dv = ndv[e];
        ag0 += dv * g[(size_t)nv[e] * C_OUT + ci];
        if (ci == 0) accd += dv;
    }
    float accg = ag0 + ag1;
    accg += __shfl_xor(accg, 16);
    accg += __shfl_xor(accg, 32);
    accd += __shfl_xor(accd, 16);
    accd += __shfl_xor(accd, 32);
    float gu = g[(size_t)u * C_OUT + ci];
    float wg = du * (du * gu + accg);   // (Wc g)_u[ci]
    float part = wg * gu;
    float sc = gu * gu;
#pragma unroll
    for (int off = 8; off; off >>= 1) {
        part += __shfl_xor(part, off, 16);
        sc += __shfl_xor(sc, off, 16);
    }
    if (j == 0) {
        float rowsum = du * (du + accd);
        pe[u] = make_float2(rowsum * sc - part, rowsum);
    }
}

// ---------------------------------------------------------------------------
// Kernel E: reduce partials, write scalar dir_energy.
// ---------------------------------------------------------------------------
__global__ __launch_bounds__(256) void finalize(
    const float2* __restrict__ pe, float* __restrict__ dout) {
    __shared__ float s0s[4], s1s[4];
    int t = threadIdx.x;
    float s0 = 0.f, s1 = 0.f;
    for (int i = t; i < N_NODES; i += 256) {
        float2 p = pe[i];
        s0 += p.x; s1 += p.y;
    }
#pragma unroll
    for (int off = 32; off; off >>= 1) {
        s0 += __shfl_xor(s0, off);
        s1 += __shfl_xor(s1, off);
    }
    if ((t & 63) == 0) { s0s[t >> 6] = s0; s1s[t >> 6] = s1; }
    __syncthreads();
    if (t == 0) {
        float a = s0s[0] + s0s[1] + s0s[2] + s0s[3];
        float b = s1s[0] + s1s[1] + s1s[2] + s1s[3];
        dout[(size_t)2 * NC] = a / b;
    }
}

extern "C" void kernel_launch(void* const* d_in, const int* in_sizes, int n_in,
                              void* d_out, int out_size, void* d_ws, size_t ws_size,
                              hipStream_t stream) {
    const float* x    = (const float*)d_in[0];
    const float* adj  = (const float*)d_in[1];
    const float* Win  = (const float*)d_in[2];
    const float* bin  = (const float*)d_in[3];
    const float* Wcv  = (const float*)d_in[4];
    const float* lng  = (const float*)d_in[5];
    const float* lnb  = (const float*)d_in[6];
    const float* Wout = (const float*)d_in[7];
    const float* bout = (const float*)d_in[8];

    char* ws = (char*)d_ws;
    size_t off = 0;
    auto alloc = [&](size_t bytes) -> void* {
        void* p = ws + off;
        off = (off + bytes + 255) & ~(size_t)255;
        return p;
    };
    int*      ell  = (int*)     alloc((size_t)N_NODES * MAXD * sizeof(int));
    int*      cnt  = (int*)     alloc((size_t)N_NODES * sizeof(int));
    float*    dinv = (float*)   alloc((size_t)N_NODES * sizeof(float));
    float*    h0   = (float*)   alloc((size_t)N_NODES * H_DIM * sizeof(float));
    ushort_t* h0b  = (ushort_t*)alloc((size_t)N_NODES * H_DIM * sizeof(ushort_t));
    ushort_t* ha   = (ushort_t*)alloc((size_t)N_NODES * H_DIM * sizeof(ushort_t));
    ushort_t* hb   = (ushort_t*)alloc((size_t)N_NODES * H_DIM * sizeof(ushort_t));
    float*    hf   = (float*)   alloc((size_t)N_NODES * H_DIM * sizeof(float));
    float*    g    = (float*)   alloc((size_t)N_NODES * C_OUT * sizeof(float));
    float2*   pe   = (float2*)  alloc((size_t)N_NODES * sizeof(float2));

    scan_and_gemm<<<N_NODES + N_NODES / GRPB, 256, 0, stream>>>(
        adj, ell, cnt, dinv, x, Win, bin, h0, h0b);

    const ushort_t* hin = h0b;
    ushort_t* bbufs[2] = { ha, hb };
    for (int i = 0; i < 4; i++) {
        float beta = logf(0.3f / (float)(i + 1) + 1.f);
        ushort_t* hbo = bbufs[i & 1];
        gcn_layer<<<N_NODES / LW, 256, 0, stream>>>(
            hin, h0, ell, cnt, dinv,
            Wcv + (size_t)i * H_DIM * H_DIM, lng + i * H_DIM, lnb + i * H_DIM,
            beta, (i != 3) ? 1 : 0, hbo, hf);
        hin = hbo;
    }

    out_head<<<N_NODES / 16, 256, 0, stream>>>(hf, Wout, bout, cnt,
                                               (float*)d_out, g);
    energy<<<N_NODES, 64, 0, stream>>>(g, ell, cnt, dinv, pe);
    finalize<<<1, 256, 0, stream>>>(pe, (float*)d_out);
}